// Round 11
// baseline (1894.630 us; speedup 1.0000x reference)
//
#include <hip/hip_runtime.h>
#include <stdint.h>
#include <stddef.h>

// ---------------------------------------------------------------------------
// PCgraph: T=32 steps of
//   mu = tanh(x) @ w^T ; e = (x-mu)*m ; g = e @ w ;
//   x = x - 0.1*m*(e - (1-tanh(x)^2)*g)
// bf16 MFMA 16x16x32, fp32 accum. x state in d_out (fp32).
// Round 20: FP8 WEIGHT PANELS on the r15 skeleton (r19 group-barriers
// reverted: 1207 vs 1032 -- LDS-atomic spin costs more than s_barrier).
// Settled model (r9-r19): phase time = staged-bytes-per-CU / ~22 B/cy; the
// cap moved for no sync/pipeline/path change. So cut bytes: both w panels
// stored fp8-e4m3 of (w * 256) -- scaling avoids e4m3 subnormals (w ~ 0.01
// would quantize at 2^-9 abs step = ~20% err; scaled, rel err ~1.8% RMS).
// The 2^-8 unscale folds EXACTLY into the fp8->bf16 decode exponent
// (bf16 = s<<15 | ((b&0x7F)<<4) + 0x3800), zero extra error; decode cost
// ~24 int-ops per 8-elem fragment, hidden under staging waits. No bf16xfp8
// MFMA exists, so B frags are dequantized to bf16 regs after ds_read_b64
// and the VERIFIED bf16 MFMA path is unchanged. A (tanh, e) stays bf16.
// mu0's one-time GEMM keeps a bf16 sensory panel (accuracy untouched).
// Staging/iter: 2x16B A + 1x16B B per thread -> vmcnt(3). LDS 96 KB.
// Predicted: phase 15.6 -> 11.8us, dur 1032 -> ~800; absmax 0.0039 ->
// 0.01-0.06 (threshold 0.089). ws end @ 34,471,936 < 256 MiB.
// ---------------------------------------------------------------------------

#define N_DIM 4096
#define B_DIM 256
#define T_STEPS 32
#define LR_X 0.1f
#define N0 768                      // first live column (aligned down from 784)
#define N_LIVE 3328                 // 4096 - 768 = 52*64
#define NCHL 52                     // live k-chunks (both GEMMs)
#define KG 4                        // k-groups per block
#define KITG 13                     // chunks per group (52/4)

typedef unsigned short ushort_t;
using bf16x8 = __attribute__((ext_vector_type(8))) __bf16;
using f32x4  = __attribute__((ext_vector_type(4))) float;

__device__ __forceinline__ ushort_t f2bf(float f) {
    union { float f; unsigned int u; } v; v.f = f;
    unsigned int r = v.u + 0x7fffu + ((v.u >> 16) & 1u);   // RNE
    return (ushort_t)(r >> 16);
}
__device__ __forceinline__ float bf2f(ushort_t h) {
    union { unsigned int u; float f; } v; v.u = ((unsigned int)h) << 16;
    return v.f;
}

// f32 -> e4m3fn of (f * 256), RNE, flush-tiny-to-zero (|f|<2^-14), clamp huge.
__device__ __forceinline__ unsigned char f2e4m3_s8(float f) {
    f *= 256.0f;
    union { float f; unsigned int u; } v; v.f = f;
    const unsigned s = (v.u >> 24) & 0x80u;
    const unsigned absu = v.u & 0x7FFFFFFFu;
    const unsigned r = absu + 0x7FFFFu + ((absu >> 20) & 1u);  // RNE to 3 mant bits
    const int e4 = (int)((r >> 23) & 0xFF) - 120;
    const unsigned m3 = (r >> 20) & 7u;
    if (e4 <= 0)  return (unsigned char)s;            // flush to +-0
    if (e4 > 15)  return (unsigned char)(s | 0x7E);   // clamp to 448/256
    return (unsigned char)(s | ((unsigned)e4 << 3) | m3);
}

// 8 fp8 (uint2) -> 8 bf16 of w (2^-8 unscale folded into exponent).
// bf16 = s<<15 | ((b&0x7F)<<4) + 0x3800  (b==+-0 decodes to +-2^-15: negligible)
__device__ __forceinline__ bf16x8 fp8x8_to_bf16x8(uint2 d) {
    union { unsigned u[4]; bf16x8 v; } o;
    unsigned x = d.x;
    o.u[0] = ((((x & 0x80u) << 8) | ((x & 0x8000u) << 16)
             | ((x & 0x7Fu) << 4) | ((x & 0x7F00u) << 12)) + 0x38003800u);
    x >>= 16;
    o.u[1] = ((((x & 0x80u) << 8) | ((x & 0x8000u) << 16)
             | ((x & 0x7Fu) << 4) | ((x & 0x7F00u) << 12)) + 0x38003800u);
    unsigned y = d.y;
    o.u[2] = ((((y & 0x80u) << 8) | ((y & 0x8000u) << 16)
             | ((y & 0x7Fu) << 4) | ((y & 0x7F00u) << 12)) + 0x38003800u);
    y >>= 16;
    o.u[3] = ((((y & 0x80u) << 8) | ((y & 0x8000u) << 16)
             | ((y & 0x7Fu) << 4) | ((y & 0x7F00u) << 12)) + 0x38003800u);
    return o.v;
}

__device__ __forceinline__ void async_copy16(const void* g, void* l) {
    __builtin_amdgcn_global_load_lds(
        (__attribute__((address_space(1))) const void*)(g),
        (__attribute__((address_space(3))) void*)(l),
        16, 0, 0);
}

// --- pack w: three jobs ------------------------------------------------------
//  bid <  624            : bf16 sensory  w_sen [52 ntile][12 chunk][4096]
//  624 <= bid < 3328     : fp8  w_live  [52 ntile][52 chunk][4096 B]  (B GEMM1)
//  3328 <= bid < 6032    : fp8  wt      [52 ntile][52 chunk][4096 B]  (B GEMM2)
__global__ __launch_bounds__(256) void pack_w(const float* __restrict__ w,
                                              ushort_t* __restrict__ wsen,
                                              uint8_t* __restrict__ wl8,
                                              uint8_t* __restrict__ wt8) {
    __shared__ float tile[64][68];
    const int tid = threadIdx.x;
    const int bid = blockIdx.x;
    int row0, col0; bool tr, f8; ushort_t* dst16 = nullptr; uint8_t* dst8 = nullptr;
    if (bid < 624) {
        tr = false; f8 = false;
        const int ntile = bid / 12, ch = bid - ntile * 12;
        row0 = N0 + ntile * 64; col0 = ch * 64;
        dst16 = wsen + (size_t)bid * 4096;
    } else if (bid < 3328) {
        tr = false; f8 = true;
        const int b2 = bid - 624;
        const int ntile = b2 / 52, cl = b2 - ntile * 52;
        row0 = N0 + ntile * 64; col0 = N0 + cl * 64;
        dst8 = wl8 + (size_t)b2 * 4096;
    } else {
        tr = true; f8 = true;
        const int b3 = bid - 3328;
        const int ntile = b3 / 52, cl = b3 - ntile * 52;
        row0 = N0 + cl * 64; col0 = N0 + ntile * 64;
        dst8 = wt8 + (size_t)b3 * 4096;
    }
    const int rr = tid >> 2, c0 = (tid & 3) * 16;
    const float* src = w + (size_t)(row0 + rr) * N_DIM + col0 + c0;
#pragma unroll
    for (int i = 0; i < 16; i += 4)
        *(float4*)&tile[rr][c0 + i] = *(const float4*)(src + i);
    __syncthreads();
    if (!f8) {
        ushort_t loc[16];
#pragma unroll
        for (int i = 0; i < 16; ++i) {
            const int p = tid * 16 + i;
            const int s = p >> 9, e = p & 511;
            const int r = ((s >> 1) << 4) | ((e >> 3) & 15);
            const int c = ((s & 1) << 5) | (((e >> 7) & 3) << 3) | (e & 7);
            loc[i] = f2bf(tile[r][c]);
        }
        *(uint4*)&dst16[tid * 16]     = *(uint4*)&loc[0];
        *(uint4*)&dst16[tid * 16 + 8] = *(uint4*)&loc[8];
    } else {
        unsigned char loc[16];
#pragma unroll
        for (int i = 0; i < 16; ++i) {
            const int p = tid * 16 + i;
            const int s = p >> 9, e = p & 511;
            const int r = ((s >> 1) << 4) | ((e >> 3) & 15);
            const int c = ((s & 1) << 5) | (((e >> 7) & 3) << 3) | (e & 7);
            loc[i] = f2e4m3_s8(tr ? tile[c][r] : tile[r][c]);
        }
        *(uint4*)&dst8[tid * 16] = *(uint4*)&loc[0];
    }
}

// --- init: x -> d_out (row-major) and t_pk [4 mtile][64 chunk][4096] --------
__global__ __launch_bounds__(256) void pack_t_init(const float* __restrict__ xin,
                                                   float* __restrict__ xout,
                                                   ushort_t* __restrict__ tpk) {
    __shared__ float tile[64][68];
    const int tid  = threadIdx.x;
    const int bid  = blockIdx.x;          // mtile*64 + chunk
    const int row0 = (bid >> 6) * 64;
    const int col0 = (bid & 63) * 64;
    const int rr = tid >> 2, c0 = (tid & 3) * 16;
    const size_t sidx = (size_t)(row0 + rr) * N_DIM + col0 + c0;
#pragma unroll
    for (int i = 0; i < 16; i += 4) {
        float4 v = *(const float4*)(xin + sidx + i);
        *(float4*)(xout + sidx + i) = v;
        tile[rr][c0 + i + 0] = tanhf(v.x);
        tile[rr][c0 + i + 1] = tanhf(v.y);
        tile[rr][c0 + i + 2] = tanhf(v.z);
        tile[rr][c0 + i + 3] = tanhf(v.w);
    }
    __syncthreads();
    ushort_t loc[16];
    ushort_t* dst = tpk + (size_t)bid * 4096;
#pragma unroll
    for (int i = 0; i < 16; ++i) {
        const int p = tid * 16 + i;
        const int s = p >> 9, e = p & 511;
        const int r = ((s >> 1) << 4) | ((e >> 3) & 15);
        const int c = ((s & 1) << 5) | (((e >> 7) & 3) << 3) | (e & 7);
        loc[i] = f2bf(tile[r][c]);
    }
    *(uint4*)&dst[tid * 16]     = *(uint4*)&loc[0];
    *(uint4*)&dst[tid * 16 + 8] = *(uint4*)&loc[8];
}

// --- one-time: mu0 = tanh(x_sensory) @ w_sensory^T (bf16 panel, chunks 0..11)
__global__ __launch_bounds__(256) void gemm_mu0(const ushort_t* __restrict__ Apk,
                                                const ushort_t* __restrict__ wsen,
                                                float* __restrict__ mu0) {
    __shared__ __align__(16) ushort_t As[2][4096];
    __shared__ __align__(16) ushort_t Bs[2][4096];
    const int tid  = threadIdx.x;
    const int lane = tid & 63;
    const int wid  = tid >> 6;
    const int wave_m = wid >> 1, wave_n = wid & 1;
    const int ntile = blockIdx.x, mtile = blockIdx.y;

    const ushort_t* Ab = Apk + (size_t)mtile * 64 * 4096;
    const ushort_t* Bb = wsen + (size_t)ntile * 12 * 4096;

    auto stage = [&](int buf, int kt) {
#pragma unroll
        for (int u = 0; u < 2; ++u) {
            const int off = (wid * 2 + u) * 512 + lane * 8;
            async_copy16(Ab + (size_t)kt * 4096 + off, &As[buf][off]);
            async_copy16(Bb + (size_t)kt * 4096 + off, &Bs[buf][off]);
        }
    };
    f32x4 acc[2][2] = {};
    auto compute = [&](int buf) {
#pragma unroll
        for (int ks = 0; ks < 2; ++ks) {
            bf16x8 a[2], b[2];
#pragma unroll
            for (int i = 0; i < 2; ++i) {
                const int asub = (wave_m * 2 + i) * 2 + ks;
                const int bsub = (wave_n * 2 + i) * 2 + ks;
                a[i] = *(const bf16x8*)(&As[buf][asub * 512 + lane * 8]);
                b[i] = *(const bf16x8*)(&Bs[buf][bsub * 512 + lane * 8]);
            }
#pragma unroll
            for (int i = 0; i < 2; ++i)
#pragma unroll
                for (int j = 0; j < 2; ++j)
                    acc[i][j] = __builtin_amdgcn_mfma_f32_16x16x32_bf16(
                        a[i], b[j], acc[i][j], 0, 0, 0);
        }
    };
    stage(0, 0);
    __syncthreads();
    for (int kt = 0; kt < 12; ++kt) {          // sensory chunks 0..11
        if (kt + 1 < 12) stage((kt + 1) & 1, kt + 1);
        compute(kt & 1);
        __syncthreads();
    }
    const int l15 = lane & 15, quad = lane >> 4;
#pragma unroll
    for (int j = 0; j < 2; ++j) {
        const int nl = ntile * 64 + wave_n * 32 + j * 16 + l15;
#pragma unroll
        for (int i = 0; i < 2; ++i)
#pragma unroll
            for (int r = 0; r < 4; ++r) {
                const int m = mtile * 64 + wave_m * 32 + i * 16 + quad * 4 + r;
                mu0[(size_t)m * N_LIVE + nl] = acc[i][j][r];
            }
    }
}

// --- fused full-K GEMM + cvt epilogue, fp8 B panels -------------------------
// Apk (bf16): [4 mtile][SA chunk][4096]; Bpk8 (fp8): [52 ntile][52 chunk][4096B].
// 208 active blocks, 1024 threads = 4 k-groups x 4 waves; group g owns live
// chunks g*13..+12. Per iter: stage A (2x16B/thread, LDS-DMA) + B (1x16B),
// vmcnt(3) keeps next tile's 3 ops in flight across the s_barrier. B frags:
// ds_read_b64 fp8 -> in-register decode to bf16 (2^-8 unscale folded).
// STAGING RULE: per-lane LDS stride EXACTLY 16B, wave-uniform base.
// f32 cross-group LDS reduction + fused cvt epilogue (r15 verbatim).
// XCD-pinned ntiles. LDS: A 64KB + B 32KB = 96KB; reduce reuses 69.6KB.
template <int SA, int CO, int PHASE>
__global__ __launch_bounds__(1024) void gemm_fused(
    const ushort_t* __restrict__ Apk,
    const uint8_t* __restrict__ Bpk8,
    float* __restrict__ xbuf,
    const float* __restrict__ mu0,
    const int* __restrict__ mask,
    ushort_t* __restrict__ epk,
    ushort_t* __restrict__ tpk) {
    __shared__ __align__(16) uint8_t smem[98304];    // 96 KB
    ushort_t* As  = (ushort_t*)smem;                  // 4 groups x 2 x 8KB
    uint8_t*  Bs8 = smem + 65536;                     // 4 groups x 2 x 4KB

    const int bid = blockIdx.x;
    const int xcd = bid & 7;
    const int i   = bid >> 3;                 // 0..31
    const int nloc = (xcd < 4) ? 7 : 6;
    if (i >= nloc * 4) return;
    const int n0    = (xcd < 4) ? xcd * 7 : 28 + (xcd - 4) * 6;
    const int ntile = n0 + (i >> 2);          // 0..51
    const int mtile = i & 3;                  // 0..3

    const int tid  = threadIdx.x;
    const int lane = tid & 63;
    const int g    = tid >> 8;                // k-group 0..3
    const int gtid = tid & 255;
    const int gw   = (tid >> 6) & 3;          // wave within group
    const int wave_m = gw >> 1, wave_n = gw & 1;

    const ushort_t* Ab = Apk + ((size_t)mtile * SA + CO + g * KITG) * 4096;
    const uint8_t*  Bb = Bpk8 + ((size_t)ntile * NCHL + g * KITG) * 4096;

    ushort_t* Asg = As + g * 2 * 4096;
    uint8_t*  Bsg = Bs8 + g * 2 * 4096;

    auto stage = [&](int buf, int kt) {
        const ushort_t* Ac = Ab + (size_t)kt * 4096;
        const uint8_t*  Bc = Bb + (size_t)kt * 4096;
#pragma unroll
        for (int u = 0; u < 2; ++u) {
            // lane stride 16B, wave-uniform base (u*4096 + gw*1024 ushorts)
            const int off = (u * 256 + gtid) * 8;
            async_copy16(Ac + off, &Asg[buf * 4096 + off]);
        }
        async_copy16(Bc + gtid * 16, &Bsg[buf * 4096 + gtid * 16]);
    };

    f32x4 acc[2][2] = {};

    auto compute = [&](int buf) {
#pragma unroll
        for (int ks = 0; ks < 2; ++ks) {
            bf16x8 a[2], b[2];
#pragma unroll
            for (int i2 = 0; i2 < 2; ++i2) {
                const int asub = (wave_m * 2 + i2) * 2 + ks;
                const int bsub = (wave_n * 2 + i2) * 2 + ks;
                a[i2] = *(const bf16x8*)(&Asg[buf * 4096 + asub * 512 + lane * 8]);
                b[i2] = fp8x8_to_bf16x8(
                    *(const uint2*)(&Bsg[buf * 4096 + bsub * 512 + lane * 8]));
            }
#pragma unroll
            for (int i2 = 0; i2 < 2; ++i2)
#pragma unroll
                for (int j = 0; j < 2; ++j)
                    acc[i2][j] = __builtin_amdgcn_mfma_f32_16x16x32_bf16(
                        a[i2], b[j], acc[i2][j], 0, 0, 0);
        }
    };

    // ---- k-loop: counted vmcnt (3 ops/stage), raw barriers -----------------
    stage(0, 0);
    for (int kt = 0; kt < KITG; ++kt) {
        if (kt + 1 < KITG) {
            stage((kt + 1) & 1, kt + 1);
            asm volatile("s_waitcnt vmcnt(3)" ::: "memory");
        } else {
            asm volatile("s_waitcnt vmcnt(0)" ::: "memory");
        }
        __builtin_amdgcn_s_barrier();
        __builtin_amdgcn_sched_barrier(0);
        compute(kt & 1);
        __builtin_amdgcn_s_barrier();
    }
    __syncthreads();                     // repurpose LDS for reduction

    // ---- cross-group f32 reduction: red[g] = 64x68-padded f32 tile ---------
    float* red = (float*)smem;           // 4 x 64*68*4B = 69.6 KB
    const int RP = 64 * 68;
    {
        const int l15 = lane & 15, quad = lane >> 4;
#pragma unroll
        for (int j = 0; j < 2; ++j) {
            const int col = wave_n * 32 + j * 16 + l15;
#pragma unroll
            for (int i2 = 0; i2 < 2; ++i2)
#pragma unroll
                for (int r = 0; r < 4; ++r) {
                    const int row = wave_m * 32 + i2 * 16 + quad * 4 + r;
                    red[g * RP + row * 68 + col] = acc[i2][j][r];
                }
        }
    }
    __syncthreads();

    // ---- fused epilogue: thread owns 4 consecutive packed positions --------
    const int p4 = tid * 4;
    const int s  = p4 >> 9, e9 = p4 & 511;
    const int r  = ((s >> 1) << 4) | ((e9 >> 3) & 15);
    const int c  = ((s & 1) << 5) | (((e9 >> 7) & 3) << 3) | (e9 & 7);

    float4 sv = *(const float4*)&red[0 * RP + r * 68 + c];
#pragma unroll
    for (int gg = 1; gg < KG; ++gg) {
        float4 v = *(const float4*)&red[gg * RP + r * 68 + c];
        sv.x += v.x; sv.y += v.y; sv.z += v.z; sv.w += v.w;
    }

    const int grow = mtile * 64 + r;          // batch row
    const int gcl  = ntile * 64 + c;          // live col
    const size_t xi = (size_t)grow * N_DIM + N0 + gcl;
    float4 xv = *(const float4*)&xbuf[xi];
    int4   mk = *(const int4*)&mask[N0 + gcl];

    if (PHASE == 1) {
        float4 m0 = *(const float4*)&mu0[(size_t)grow * N_LIVE + gcl];
        ushort_t ev[4];
        ev[0] = f2bf((xv.x - (m0.x + sv.x)) * (float)mk.x);
        ev[1] = f2bf((xv.y - (m0.y + sv.y)) * (float)mk.y);
        ev[2] = f2bf((xv.z - (m0.z + sv.z)) * (float)mk.z);
        ev[3] = f2bf((xv.w - (m0.w + sv.w)) * (float)mk.w);
        *(uint2*)&epk[((size_t)(mtile * NCHL + ntile)) * 4096 + p4]
            = *(uint2*)&ev[0];
    } else {
        // e read back through Apk (Apk IS e_pk in phase 2; same packed chunk)
        const ushort_t* ech = Apk + ((size_t)(mtile * SA + ntile)) * 4096;
        ushort_t ein[4];
        *(uint2*)&ein[0] = *(const uint2*)&ech[p4];
        float xn[4]; ushort_t tv[4];
        const float* svp = &sv.x;
        const int*   mkp = &mk.x;
        const float* xvp = &xv.x;
#pragma unroll
        for (int q = 0; q < 4; ++q) {
            const float x  = xvp[q];
            const float th = tanhf(x);
            const float ee = bf2f(ein[q]);
            xn[q] = x - LR_X * (float)mkp[q] * (ee - (1.0f - th * th) * svp[q]);
            tv[q] = f2bf(tanhf(xn[q]));
        }
        *(float4*)&xbuf[xi] = make_float4(xn[0], xn[1], xn[2], xn[3]);
        *(uint2*)&tpk[((size_t)(mtile * 64 + 12 + ntile)) * 4096 + p4]
            = *(uint2*)&tv[0];
    }
}

extern "C" void kernel_launch(void* const* d_in, const int* in_sizes, int n_in,
                              void* d_out, int out_size, void* d_ws, size_t ws_size,
                              hipStream_t stream) {
    const float* x_in  = (const float*)d_in[0];
    const float* w_in  = (const float*)d_in[1];
    const int*   mask  = (const int*)d_in[2];
    float*       xbuf  = (float*)d_out;          // state lives in d_out

    uint8_t* ws = (uint8_t*)d_ws;
    // ws layout (end @ 34,471,936 bytes; ws_size = 256 MiB per fillBuffer):
    ushort_t* w_sen = (ushort_t*)(ws);                   // 52*12*4096*2 =  5,111,808
    uint8_t*  w_l8  = (uint8_t*)(ws + 5111808);          // 52*52*4096   = 11,075,584
    uint8_t*  wt_8  = (uint8_t*)(ws + 16187392);         // 52*52*4096   = 11,075,584
    ushort_t* t_pk  = (ushort_t*)(ws + 27262976);        //  4*64*4096*2 =  2,097,152
    ushort_t* e_pk  = (ushort_t*)(ws + 29360128);        //  4*52*4096*2 =  1,703,936
    float*    mu0   = (float*)(ws + 31064064);           //  256*3328*4  =  3,407,872

    pack_w<<<dim3(6032), 256, 0, stream>>>(w_in, w_sen, w_l8, wt_8);
    pack_t_init<<<dim3(4 * 64), 256, 0, stream>>>(x_in, xbuf, t_pk);
    gemm_mu0<<<dim3(52, 4), 256, 0, stream>>>(t_pk, w_sen, mu0);

    for (int t = 0; t < T_STEPS; ++t) {
        // GEMM1+cvt1: e = (x - mu)*mask -> e_pk   (A = t_pk, B = w_l8 fp8)
        gemm_fused<64, 12, 1><<<256, 1024, 0, stream>>>(
            t_pk, w_l8, xbuf, mu0, mask, e_pk, t_pk);
        // GEMM2+cvt2: x update -> xbuf, tanh -> t_pk (A = e_pk, B = wt_8 fp8)
        gemm_fused<52, 0, 2><<<256, 1024, 0, stream>>>(
            e_pk, wt_8, xbuf, mu0, mask, e_pk, t_pk);
    }
}

// Round 12
// 830.581 us; speedup vs baseline: 2.2811x; 2.2811x over previous
//
#include <hip/hip_runtime.h>
#include <stdint.h>
#include <stddef.h>

// ---------------------------------------------------------------------------
// PCgraph: T=32 steps of
//   mu = tanh(x) @ w^T ; e = (x-mu)*m ; g = e @ w ;
//   x = x - 0.1*m*(e - (1-tanh(x)^2)*g)
// Round 21: NATIVE FP8 MFMA (mfma_f32_16x16x32_fp8_fp8), zero dequant.
// r20 proved fp8 accuracy (absmax 0.026) but its software dequant cost more
// VALU than the bytes saved (1894us). Fix: quantize BOTH GEMM operands to
// e4m3 and feed the native fp8 MFMA (same shape / elems-per-lane / C-layout
// as the verified bf16 path; r20 already HW-validated the fp8 packed-chunk
// byte order via its dequant path). w panels stored as e4m3(w*256) -- the
// 2^-8 folds exactly into the epilogue (sv/256). tanh and e stored e4m3
// direct (subnormal-encoded near 0). The x-update still reads e from a
// bf16 copy (e_bf), so update precision is r15-level; fp8 e only feeds the
// g-GEMM. Staging: 2x16B/thread/iter (A 4KB + B 4KB chunk), vmcnt(2),
// counted across the s_barrier; STAGING RULE: per-lane LDS stride EXACTLY
// 16B, wave-uniform base. Staged bytes/phase: 832 -> 416 KB/block.
// Skeleton otherwise r15 (best verified: 1032us): 2 fused dispatches/step,
// 208 active blocks (52 ntile x 4 mtile), 1024 thr = 4 k-groups x 4 waves,
// f32 cross-group LDS reduction, fused cvt epilogues, XCD-pinned ntiles,
// bf16 one-time mu0 path. ws end @ 34,471,936 < 256 MiB.
// Predicted: phase ~8us, dur ~650-800us, absmax 0.04-0.06 (thr 0.089).
// ---------------------------------------------------------------------------

#define N_DIM 4096
#define B_DIM 256
#define T_STEPS 32
#define LR_X 0.1f
#define N0 768                      // first live column (aligned down from 784)
#define N_LIVE 3328                 // 4096 - 768 = 52*64
#define NCHL 52                     // live k-chunks (both GEMMs)
#define KG 4                        // k-groups per block
#define KITG 13                     // chunks per group (52/4)

typedef unsigned short ushort_t;
using bf16x8 = __attribute__((ext_vector_type(8))) __bf16;
using f32x4  = __attribute__((ext_vector_type(4))) float;

__device__ __forceinline__ ushort_t f2bf(float f) {
    union { float f; unsigned int u; } v; v.f = f;
    unsigned int r = v.u + 0x7fffu + ((v.u >> 16) & 1u);   // RNE
    return (ushort_t)(r >> 16);
}
__device__ __forceinline__ float bf2f(ushort_t h) {
    union { unsigned int u; float f; } v; v.u = ((unsigned int)h) << 16;
    return v.f;
}

// f32 -> e4m3fn (OCP), RNE, subnormal-encoded, clamped to +-448 (no NaN).
__device__ __forceinline__ unsigned char f2e4m3(float f) {
    union { float f; unsigned int u; } v; v.f = f;
    const unsigned s = (v.u >> 24) & 0x80u;
    const unsigned absu = v.u & 0x7FFFFFFFu;
    const unsigned r = absu + 0x7FFFFu + ((absu >> 20) & 1u);  // RNE to 3 mant
    const int e4 = (int)((r >> 23) & 0xFF) - 120;
    const unsigned m3 = (r >> 20) & 7u;
    if (e4 <= 0) {                      // subnormal: m = round(|f| * 512)
        union { unsigned u; float f; } a; a.u = absu;
        int m = (int)(a.f * 512.0f + 0.5f);
        if (m > 7) return (unsigned char)(s | 0x08);   // rounds up to 2^-6
        return (unsigned char)(s | (unsigned)m);
    }
    if (e4 > 15 || (e4 == 15 && m3 == 7))
        return (unsigned char)(s | 0x7E);              // clamp to 448
    return (unsigned char)(s | ((unsigned)e4 << 3) | m3);
}

__device__ __forceinline__ void async_copy16(const void* g, void* l) {
    __builtin_amdgcn_global_load_lds(
        (__attribute__((address_space(1))) const void*)(g),
        (__attribute__((address_space(3))) void*)(l),
        16, 0, 0);
}

// --- pack w: three jobs ------------------------------------------------------
//  bid <  624        : bf16 sensory w_sen [52 ntile][12 chunk][4096] (mu0 B)
//  624 <= bid < 3328 : fp8 e4m3(w*256) w_l8 [52 nt][52 ch][4096B] (B GEMM1)
//  3328 <= bid < 6032: fp8 e4m3(w*256) wt_8 [52 nt][52 ch][4096B] (B GEMM2, w^T)
__global__ __launch_bounds__(256) void pack_w(const float* __restrict__ w,
                                              ushort_t* __restrict__ wsen,
                                              uint8_t* __restrict__ wl8,
                                              uint8_t* __restrict__ wt8) {
    __shared__ float tile[64][68];
    const int tid = threadIdx.x;
    const int bid = blockIdx.x;
    int row0, col0; bool tr, f8; ushort_t* dst16 = nullptr; uint8_t* dst8 = nullptr;
    if (bid < 624) {
        tr = false; f8 = false;
        const int ntile = bid / 12, ch = bid - ntile * 12;
        row0 = N0 + ntile * 64; col0 = ch * 64;
        dst16 = wsen + (size_t)bid * 4096;
    } else if (bid < 3328) {
        tr = false; f8 = true;
        const int b2 = bid - 624;
        const int ntile = b2 / 52, cl = b2 - ntile * 52;
        row0 = N0 + ntile * 64; col0 = N0 + cl * 64;
        dst8 = wl8 + (size_t)b2 * 4096;
    } else {
        tr = true; f8 = true;
        const int b3 = bid - 3328;
        const int ntile = b3 / 52, cl = b3 - ntile * 52;
        row0 = N0 + cl * 64; col0 = N0 + ntile * 64;
        dst8 = wt8 + (size_t)b3 * 4096;
    }
    const int rr = tid >> 2, c0 = (tid & 3) * 16;
    const float* src = w + (size_t)(row0 + rr) * N_DIM + col0 + c0;
#pragma unroll
    for (int i = 0; i < 16; i += 4)
        *(float4*)&tile[rr][c0 + i] = *(const float4*)(src + i);
    __syncthreads();
    if (!f8) {
        ushort_t loc[16];
#pragma unroll
        for (int i = 0; i < 16; ++i) {
            const int p = tid * 16 + i;
            const int s = p >> 9, e = p & 511;
            const int r = ((s >> 1) << 4) | ((e >> 3) & 15);
            const int c = ((s & 1) << 5) | (((e >> 7) & 3) << 3) | (e & 7);
            loc[i] = f2bf(tile[r][c]);
        }
        *(uint4*)&dst16[tid * 16]     = *(uint4*)&loc[0];
        *(uint4*)&dst16[tid * 16 + 8] = *(uint4*)&loc[8];
    } else {
        unsigned char loc[16];
#pragma unroll
        for (int i = 0; i < 16; ++i) {
            const int p = tid * 16 + i;
            const int s = p >> 9, e = p & 511;
            const int r = ((s >> 1) << 4) | ((e >> 3) & 15);
            const int c = ((s & 1) << 5) | (((e >> 7) & 3) << 3) | (e & 7);
            loc[i] = f2e4m3((tr ? tile[c][r] : tile[r][c]) * 256.0f);
        }
        *(uint4*)&dst8[tid * 16] = *(uint4*)&loc[0];
    }
}

// --- init: x -> d_out, tanh -> t_sen (bf16, chunks 0..11) + t_pk8 (fp8, live)
__global__ __launch_bounds__(256) void pack_t_init(const float* __restrict__ xin,
                                                   float* __restrict__ xout,
                                                   ushort_t* __restrict__ tsen,
                                                   uint8_t* __restrict__ tpk8) {
    __shared__ float tile[64][68];
    const int tid  = threadIdx.x;
    const int bid  = blockIdx.x;          // mtile*64 + chunk
    const int mt   = bid >> 6;
    const int ch   = bid & 63;
    const int row0 = mt * 64;
    const int col0 = ch * 64;
    const int rr = tid >> 2, c0 = (tid & 3) * 16;
    const size_t sidx = (size_t)(row0 + rr) * N_DIM + col0 + c0;
#pragma unroll
    for (int i = 0; i < 16; i += 4) {
        float4 v = *(const float4*)(xin + sidx + i);
        *(float4*)(xout + sidx + i) = v;
        tile[rr][c0 + i + 0] = tanhf(v.x);
        tile[rr][c0 + i + 1] = tanhf(v.y);
        tile[rr][c0 + i + 2] = tanhf(v.z);
        tile[rr][c0 + i + 3] = tanhf(v.w);
    }
    __syncthreads();
    if (ch < 12) {
        ushort_t loc[16];
        ushort_t* dst = tsen + (size_t)(mt * 12 + ch) * 4096;
#pragma unroll
        for (int i = 0; i < 16; ++i) {
            const int p = tid * 16 + i;
            const int s = p >> 9, e = p & 511;
            const int r = ((s >> 1) << 4) | ((e >> 3) & 15);
            const int c = ((s & 1) << 5) | (((e >> 7) & 3) << 3) | (e & 7);
            loc[i] = f2bf(tile[r][c]);
        }
        *(uint4*)&dst[tid * 16]     = *(uint4*)&loc[0];
        *(uint4*)&dst[tid * 16 + 8] = *(uint4*)&loc[8];
    } else {
        unsigned char loc[16];
        uint8_t* dst = tpk8 + (size_t)(mt * NCHL + ch - 12) * 4096;
#pragma unroll
        for (int i = 0; i < 16; ++i) {
            const int p = tid * 16 + i;
            const int s = p >> 9, e = p & 511;
            const int r = ((s >> 1) << 4) | ((e >> 3) & 15);
            const int c = ((s & 1) << 5) | (((e >> 7) & 3) << 3) | (e & 7);
            loc[i] = f2e4m3(tile[r][c]);
        }
        *(uint4*)&dst[tid * 16] = *(uint4*)&loc[0];
    }
}

// --- one-time: mu0 = tanh(x_sensory) @ w_sensory^T (bf16 panels, exact path)
__global__ __launch_bounds__(256) void gemm_mu0(const ushort_t* __restrict__ tsen,
                                                const ushort_t* __restrict__ wsen,
                                                float* __restrict__ mu0) {
    __shared__ __align__(16) ushort_t As[2][4096];
    __shared__ __align__(16) ushort_t Bs[2][4096];
    const int tid  = threadIdx.x;
    const int lane = tid & 63;
    const int wid  = tid >> 6;
    const int wave_m = wid >> 1, wave_n = wid & 1;
    const int ntile = blockIdx.x, mtile = blockIdx.y;

    const ushort_t* Ab = tsen + (size_t)mtile * 12 * 4096;
    const ushort_t* Bb = wsen + (size_t)ntile * 12 * 4096;

    auto stage = [&](int buf, int kt) {
#pragma unroll
        for (int u = 0; u < 2; ++u) {
            const int off = (wid * 2 + u) * 512 + lane * 8;
            async_copy16(Ab + (size_t)kt * 4096 + off, &As[buf][off]);
            async_copy16(Bb + (size_t)kt * 4096 + off, &Bs[buf][off]);
        }
    };
    f32x4 acc[2][2] = {};
    auto compute = [&](int buf) {
#pragma unroll
        for (int ks = 0; ks < 2; ++ks) {
            bf16x8 a[2], b[2];
#pragma unroll
            for (int i = 0; i < 2; ++i) {
                const int asub = (wave_m * 2 + i) * 2 + ks;
                const int bsub = (wave_n * 2 + i) * 2 + ks;
                a[i] = *(const bf16x8*)(&As[buf][asub * 512 + lane * 8]);
                b[i] = *(const bf16x8*)(&Bs[buf][bsub * 512 + lane * 8]);
            }
#pragma unroll
            for (int i = 0; i < 2; ++i)
#pragma unroll
                for (int j = 0; j < 2; ++j)
                    acc[i][j] = __builtin_amdgcn_mfma_f32_16x16x32_bf16(
                        a[i], b[j], acc[i][j], 0, 0, 0);
        }
    };
    stage(0, 0);
    __syncthreads();
    for (int kt = 0; kt < 12; ++kt) {          // sensory chunks 0..11
        if (kt + 1 < 12) stage((kt + 1) & 1, kt + 1);
        compute(kt & 1);
        __syncthreads();
    }
    const int l15 = lane & 15, quad = lane >> 4;
#pragma unroll
    for (int j = 0; j < 2; ++j) {
        const int nl = ntile * 64 + wave_n * 32 + j * 16 + l15;
#pragma unroll
        for (int i = 0; i < 2; ++i)
#pragma unroll
            for (int r = 0; r < 4; ++r) {
                const int m = mtile * 64 + wave_m * 32 + i * 16 + quad * 4 + r;
                mu0[(size_t)m * N_LIVE + nl] = acc[i][j][r];
            }
    }
}

// --- fused full-K fp8 GEMM + cvt epilogue -----------------------------------
// Apk8/Bpk8 (fp8): [4 mtile / 52 ntile][52 chunk][4096 B]. 208 active blocks,
// 1024 threads = 4 k-groups x 4 waves; group g owns live chunks g*13..+12.
// Per iter: 1x16B A copy + 1x16B B copy per thread (LDS-DMA), vmcnt(2)
// keeps next tile's 2 ops in flight across the s_barrier. Compute: native
// fp8 MFMA, A/B fragments read as long (8B/lane). Products carry the w*256
// scale -> epilogue multiplies sv by 2^-8 (exact). PHASE1 writes e as bf16
// (e_bf, for the phase-2 x-update) AND e4m3 (e8, GEMM2's A operand).
// PHASE2 reads e_bf, updates x, writes tanh(xn) as e4m3 to t8.
// f32 cross-group LDS reduction (r15 verbatim). XCD-pinned ntiles.
template <int PHASE>
__global__ __launch_bounds__(1024) void gemm_fused(
    const uint8_t* __restrict__ Apk8,
    const uint8_t* __restrict__ Bpk8,
    float* __restrict__ xbuf,
    const float* __restrict__ mu0,
    const int* __restrict__ mask,
    ushort_t* __restrict__ e_bf,
    uint8_t* __restrict__ e8,
    uint8_t* __restrict__ t8) {
    __shared__ __align__(16) uint8_t smem[69632];    // 68 KB (reduce needs 69632)
    uint8_t* As = smem;                               // 4 groups x 2 x 4KB
    uint8_t* Bs = smem + 32768;                       // 4 groups x 2 x 4KB

    const int bid = blockIdx.x;
    const int xcd = bid & 7;
    const int i   = bid >> 3;                 // 0..31
    const int nloc = (xcd < 4) ? 7 : 6;
    if (i >= nloc * 4) return;
    const int n0    = (xcd < 4) ? xcd * 7 : 28 + (xcd - 4) * 6;
    const int ntile = n0 + (i >> 2);          // 0..51
    const int mtile = i & 3;                  // 0..3

    const int tid  = threadIdx.x;
    const int lane = tid & 63;
    const int g    = tid >> 8;                // k-group 0..3
    const int gtid = tid & 255;
    const int gw   = (tid >> 6) & 3;          // wave within group
    const int wave_m = gw >> 1, wave_n = gw & 1;

    const uint8_t* Ab = Apk8 + ((size_t)(mtile * NCHL) + g * KITG) * 4096;
    const uint8_t* Bb = Bpk8 + ((size_t)(ntile * NCHL) + g * KITG) * 4096;

    uint8_t* Asg = As + g * 2 * 4096;
    uint8_t* Bsg = Bs + g * 2 * 4096;

    auto stage = [&](int buf, int kt) {
        // lane stride 16B, wave-uniform base (gw*1024 bytes within the group)
        async_copy16(Ab + (size_t)kt * 4096 + gtid * 16,
                     &Asg[buf * 4096 + gtid * 16]);
        async_copy16(Bb + (size_t)kt * 4096 + gtid * 16,
                     &Bsg[buf * 4096 + gtid * 16]);
    };

    f32x4 acc[2][2] = {};

    auto compute = [&](int buf) {
#pragma unroll
        for (int ks = 0; ks < 2; ++ks) {
            long a[2], b[2];
#pragma unroll
            for (int i2 = 0; i2 < 2; ++i2) {
                const int asub = (wave_m * 2 + i2) * 2 + ks;
                const int bsub = (wave_n * 2 + i2) * 2 + ks;
                a[i2] = *(const long*)(&Asg[buf * 4096 + asub * 512 + lane * 8]);
                b[i2] = *(const long*)(&Bsg[buf * 4096 + bsub * 512 + lane * 8]);
            }
#pragma unroll
            for (int i2 = 0; i2 < 2; ++i2)
#pragma unroll
                for (int j = 0; j < 2; ++j)
                    acc[i2][j] = __builtin_amdgcn_mfma_f32_16x16x32_fp8_fp8(
                        a[i2], b[j], acc[i2][j], 0, 0, 0);
        }
    };

    // ---- k-loop: counted vmcnt (2 ops/stage), raw barriers -----------------
    stage(0, 0);
    for (int kt = 0; kt < KITG; ++kt) {
        if (kt + 1 < KITG) {
            stage((kt + 1) & 1, kt + 1);
            asm volatile("s_waitcnt vmcnt(2)" ::: "memory");
        } else {
            asm volatile("s_waitcnt vmcnt(0)" ::: "memory");
        }
        __builtin_amdgcn_s_barrier();
        __builtin_amdgcn_sched_barrier(0);
        compute(kt & 1);
        __builtin_amdgcn_s_barrier();
    }
    __syncthreads();                     // repurpose LDS for reduction

    // ---- cross-group f32 reduction: red[g] = 64x68-padded f32 tile ---------
    float* red = (float*)smem;           // 4 x 64*68*4B = 69632 B
    const int RP = 64 * 68;
    {
        const int l15 = lane & 15, quad = lane >> 4;
#pragma unroll
        for (int j = 0; j < 2; ++j) {
            const int col = wave_n * 32 + j * 16 + l15;
#pragma unroll
            for (int i2 = 0; i2 < 2; ++i2)
#pragma unroll
                for (int r = 0; r < 4; ++r) {
                    const int row = wave_m * 32 + i2 * 16 + quad * 4 + r;
                    red[g * RP + row * 68 + col] = acc[i2][j][r];
                }
        }
    }
    __syncthreads();

    // ---- fused epilogue: thread owns 4 consecutive packed positions --------
    const int p4 = tid * 4;
    const int s  = p4 >> 9, e9 = p4 & 511;
    const int r  = ((s >> 1) << 4) | ((e9 >> 3) & 15);
    const int c  = ((s & 1) << 5) | (((e9 >> 7) & 3) << 3) | (e9 & 7);

    float4 sv = *(const float4*)&red[0 * RP + r * 68 + c];
#pragma unroll
    for (int gg = 1; gg < KG; ++gg) {
        float4 v = *(const float4*)&red[gg * RP + r * 68 + c];
        sv.x += v.x; sv.y += v.y; sv.z += v.z; sv.w += v.w;
    }
    const float INV = 0.00390625f;       // 2^-8: undo the w*256 scale (exact)
    sv.x *= INV; sv.y *= INV; sv.z *= INV; sv.w *= INV;

    const int grow = mtile * 64 + r;          // batch row
    const int gcl  = ntile * 64 + c;          // live col
    const size_t xi = (size_t)grow * N_DIM + N0 + gcl;
    float4 xv = *(const float4*)&xbuf[xi];
    int4   mk = *(const int4*)&mask[N0 + gcl];
    const size_t choff = (size_t)(mtile * NCHL + ntile) * 4096;

    if (PHASE == 1) {
        float4 m0 = *(const float4*)&mu0[(size_t)grow * N_LIVE + gcl];
        float ef[4];
        ef[0] = (xv.x - (m0.x + sv.x)) * (float)mk.x;
        ef[1] = (xv.y - (m0.y + sv.y)) * (float)mk.y;
        ef[2] = (xv.z - (m0.z + sv.z)) * (float)mk.z;
        ef[3] = (xv.w - (m0.w + sv.w)) * (float)mk.w;
        ushort_t ev[4] = { f2bf(ef[0]), f2bf(ef[1]), f2bf(ef[2]), f2bf(ef[3]) };
        *(uint2*)&e_bf[choff + p4] = *(uint2*)&ev[0];
        unsigned char e8v[4] = { f2e4m3(ef[0]), f2e4m3(ef[1]),
                                 f2e4m3(ef[2]), f2e4m3(ef[3]) };
        *(unsigned*)&e8[choff + p4] = *(unsigned*)&e8v[0];
    } else {
        ushort_t ein[4];
        *(uint2*)&ein[0] = *(const uint2*)&e_bf[choff + p4];
        float xn[4]; unsigned char tv[4];
        const float* svp = &sv.x;
        const int*   mkp = &mk.x;
        const float* xvp = &xv.x;
#pragma unroll
        for (int q = 0; q < 4; ++q) {
            const float x  = xvp[q];
            const float th = tanhf(x);
            const float ee = bf2f(ein[q]);
            xn[q] = x - LR_X * (float)mkp[q] * (ee - (1.0f - th * th) * svp[q]);
            tv[q] = f2e4m3(tanhf(xn[q]));
        }
        *(float4*)&xbuf[xi] = make_float4(xn[0], xn[1], xn[2], xn[3]);
        *(unsigned*)&t8[choff + p4] = *(unsigned*)&tv[0];
    }
}

extern "C" void kernel_launch(void* const* d_in, const int* in_sizes, int n_in,
                              void* d_out, int out_size, void* d_ws, size_t ws_size,
                              hipStream_t stream) {
    const float* x_in  = (const float*)d_in[0];
    const float* w_in  = (const float*)d_in[1];
    const int*   mask  = (const int*)d_in[2];
    float*       xbuf  = (float*)d_out;          // state lives in d_out

    uint8_t* ws = (uint8_t*)d_ws;
    // ws layout (end @ 34,471,936 bytes; ws_size = 256 MiB per fillBuffer):
    ushort_t* w_sen = (ushort_t*)(ws);                   // 52*12*4096*2 =  5,111,808
    uint8_t*  w_l8  = (uint8_t*)(ws + 5111808);          // 52*52*4096   = 11,075,584
    uint8_t*  wt_8  = (uint8_t*)(ws + 16187392);         // 52*52*4096   = 11,075,584
    ushort_t* t_sen = (ushort_t*)(ws + 27262976);        //  4*12*4096*2 =    393,216
    uint8_t*  t_pk8 = (uint8_t*)(ws + 27656192);         //  4*52*4096   =    851,968
    ushort_t* e_bf  = (ushort_t*)(ws + 28508160);        //  4*52*4096*2 =  1,703,936
    uint8_t*  e_pk8 = (uint8_t*)(ws + 30212096);         //  4*52*4096   =    851,968
    float*    mu0   = (float*)(ws + 31064064);           //  256*3328*4  =  3,407,872

    pack_w<<<dim3(6032), 256, 0, stream>>>(w_in, w_sen, w_l8, wt_8);
    pack_t_init<<<dim3(4 * 64), 256, 0, stream>>>(x_in, xbuf, t_sen, t_pk8);
    gemm_mu0<<<dim3(52, 4), 256, 0, stream>>>(t_sen, w_sen, mu0);

    for (int t = 0; t < T_STEPS; ++t) {
        // GEMM1+cvt1: e = (x - mu)*mask -> e_bf + e_pk8  (A = t_pk8, B = w_l8)
        gemm_fused<1><<<256, 1024, 0, stream>>>(
            t_pk8, w_l8, xbuf, mu0, mask, e_bf, e_pk8, t_pk8);
        // GEMM2+cvt2: x update -> xbuf, tanh -> t_pk8    (A = e_pk8, B = wt_8)
        gemm_fused<2><<<256, 1024, 0, stream>>>(
            e_pk8, wt_8, xbuf, mu0, mask, e_bf, e_pk8, t_pk8);
    }
}